// Round 11
// baseline (1116.371 us; speedup 1.0000x reference)
//
#include <hip/hip_runtime.h>
#include <hip/hip_bf16.h>

#define HID 100
#define TT 750
#define NB_TOT 1024
#define ALPHA 0.01f
#define NSTD 0.1f

typedef __bf16 bf16x8 __attribute__((ext_vector_type(8)));
typedef float floatx4 __attribute__((ext_vector_type(4)));

__device__ __forceinline__ float fast_tanh(float v) {
    // tanh(v) = 1 - 2/(exp(2v)+1); graceful at +-inf, abs err ~1e-6
    float e = __expf(2.0f * v);
    return 1.0f - 2.0f / (e + 1.0f);
}

struct Pf { float nA0, nA1, nB0, nB1; floatx4 u0, u1; };

// ONE WAVE PER BLOCK — zero barriers in the 750-step loop. The wave owns
// 2 batches entirely: J (hi/lo split, K=96) lives in registers/AGPRs
// (~300 regs incl. prefetch; m08: no spill through ~450), LDS is only a
// 512B private transpose scratch ordered by lgkmcnt. 512 blocks over
// 1024 SIMDs => no MFMA contention, occupancy intentionally ~6%.
__global__ __launch_bounds__(64, 1)
void rnn_kernel(const float* __restrict__ useq,   // [750][1024][4]
                const float* __restrict__ noise,  // [750][1024][100]
                const float* __restrict__ Jw,     // [100][100]
                const float* __restrict__ Bm,     // [4][100]
                const float* __restrict__ cxp,    // [100]
                const float* __restrict__ Ww,     // [100]
                const float* __restrict__ Wb,     // [1]
                float* __restrict__ out)          // [1024]
{
    // r scratch: [batch][128 bf16]. k in [100,128) stays zero from init.
    __shared__ __align__(16) __bf16 rbuf[2][128];
    __shared__ float red[2][112];

    const int lane = threadIdx.x;   // 0..63
    const int m16  = lane & 15;
    const int q    = lane >> 4;     // 0..3
    const int wg   = blockIdx.x;
    const int gb0  = wg * 2;

    // Update assignment: lane handles tiles tiA=q and tiB=q+4 (both batches).
    // Clamped-A duplication (R8-verified): C row m = y[batch m&1], so group q
    // regs 0,1 of ANY tile's acc = y[b0],y[b1] at col m16.
    const int  hA  = q * 16 + m16;          // 0..63 — always valid
    const int  hB  = hA + 64;               // 64..111
    const bool vB  = (hB < HID);
    const int  hBc = vB ? hB : 0;

    // zero rbuf: 2*128*2B = 512B = 128 dwords
    ((float*)rbuf)[lane]      = 0.0f;
    ((float*)rbuf)[lane + 64] = 0.0f;

    // --- J fragments (B operand), K=96 in MFMA, hi/lo bf16 split ---
    // B layout: col = lane&15 -> J row ti*16+m16; k = s*32 + q*8 + j
    bf16x8 jhi[7][3], jlo[7][3];
    #pragma unroll
    for (int ti = 0; ti < 7; ++ti) {
        const int ht = ti * 16 + m16;
        #pragma unroll
        for (int s = 0; s < 3; ++s) {
            bf16x8 vh, vl;
            #pragma unroll
            for (int j = 0; j < 8; ++j) {
                const int k = s * 32 + q * 8 + j;
                float jv = (ht < HID) ? Jw[ht * HID + k] : 0.0f;
                __bf16 hi = (__bf16)jv;
                vh[j] = hi;
                vl[j] = (__bf16)(jv - (float)hi);
            }
            jhi[ti][s] = vh; jlo[ti][s] = vl;
        }
    }

    // --- k=96..99 tail J (fp32 exact) + per-h constants for hA and hB ---
    floatx4 jtA, jtB, bmA, bmB;
    #pragma unroll
    for (int j = 0; j < 4; ++j) {
        jtA[j] = Jw[hA * HID + 96 + j];
        jtB[j] = vB ? Jw[hB * HID + 96 + j] : 0.0f;
        bmA[j] = Bm[j * HID + hA];
        bmB[j] = vB ? Bm[j * HID + hB] : 0.0f;
    }
    const float cxA = cxp[hA], wA = Ww[hA];
    const float cxB = vB ? cxp[hB] : 0.0f, wB = vB ? Ww[hB] : 0.0f;

    // --- prefetch (depth 4): 4 noise scalars + 2 broadcast u float4 ---
    const float* nA = noise + (size_t)gb0 * HID + hA;    // +HID for batch1
    const float* nB = noise + (size_t)gb0 * HID + hBc;
    const float* up = useq  + (size_t)gb0 * 4;

    auto pfetch = [&](int t, Pf& P) {
        const size_t to = (size_t)t * (NB_TOT * HID);
        P.nA0 = nA[to]; P.nA1 = nA[to + HID];
        P.nB0 = nB[to]; P.nB1 = nB[to + HID];
        const float* u = up + (size_t)t * (NB_TOT * 4);
        P.u0 = *(const floatx4*)u;
        P.u1 = *(const floatx4*)(u + 4);
    };

    Pf p0, p1, p2, p3;
    pfetch(0, p0); pfetch(1, p1); pfetch(2, p2); pfetch(3, p3);

    float xA0 = 0.f, xA1 = 0.f, xB0 = 0.f, xB1 = 0.f;

    // A-frag reads: row clamped to m16&1, chunk = s*4+q (k = 32s+8q+j).
    // 8 distinct addrs/instr; rows 0/1 are 256B apart -> same banks, 2-way
    // (free, m136). Tail reads are wave-uniform (pure broadcast).
    const int aidx = (m16 & 1) * 16;

    auto step = [&](int T, Pf& P) {
        const bf16x8* rb = (const bf16x8*)rbuf;
        bf16x8 afr[3];
        #pragma unroll
        for (int s = 0; s < 3; ++s) afr[s] = rb[aidx + s * 4 + q];
        const uint2 t0 = *(const uint2*)(&rbuf[0][96]);   // r[b0][96..99]
        const uint2 t1 = *(const uint2*)(&rbuf[1][96]);   // r[b1][96..99]

        // ---- base terms (prefetched inputs are 4 steps old) ----
        const float r96a = __uint_as_float((t0.x & 0xffffu) << 16);
        const float r97a = __uint_as_float(t0.x & 0xffff0000u);
        const float r98a = __uint_as_float((t0.y & 0xffffu) << 16);
        const float r99a = __uint_as_float(t0.y & 0xffff0000u);
        const float r96b = __uint_as_float((t1.x & 0xffffu) << 16);
        const float r97b = __uint_as_float(t1.x & 0xffff0000u);
        const float r98b = __uint_as_float((t1.y & 0xffffu) << 16);
        const float r99b = __uint_as_float(t1.y & 0xffff0000u);
        const float tdA0 = r96a*jtA[0] + r97a*jtA[1] + r98a*jtA[2] + r99a*jtA[3];
        const float tdA1 = r96b*jtA[0] + r97b*jtA[1] + r98b*jtA[2] + r99b*jtA[3];
        const float tdB0 = r96a*jtB[0] + r97a*jtB[1] + r98a*jtB[2] + r99a*jtB[3];
        const float tdB1 = r96b*jtB[0] + r97b*jtB[1] + r98b*jtB[2] + r99b*jtB[3];
        const float dA0 = P.u0[0]*bmA[0] + P.u0[1]*bmA[1] + P.u0[2]*bmA[2] + P.u0[3]*bmA[3];
        const float dA1 = P.u1[0]*bmA[0] + P.u1[1]*bmA[1] + P.u1[2]*bmA[2] + P.u1[3]*bmA[3];
        const float dB0 = P.u0[0]*bmB[0] + P.u0[1]*bmB[1] + P.u0[2]*bmB[2] + P.u0[3]*bmB[3];
        const float dB1 = P.u1[0]*bmB[0] + P.u1[1]*bmB[1] + P.u1[2]*bmB[2] + P.u1[3]*bmB[3];
        const float baseA0 = xA0*(1.0f-ALPHA) + ALPHA*(dA0 + cxA + NSTD*P.nA0 + tdA0);
        const float baseA1 = xA1*(1.0f-ALPHA) + ALPHA*(dA1 + cxA + NSTD*P.nA1 + tdA1);
        const float baseB0 = xB0*(1.0f-ALPHA) + ALPHA*(dB0 + cxB + NSTD*P.nB0 + tdB0);
        const float baseB1 = xB1*(1.0f-ALPHA) + ALPHA*(dB1 + cxB + NSTD*P.nB1 + tdB1);

        // ---- MFMA: 7 tiles x K=96, hi+lo share one acc (7 indep chains) ----
        floatx4 a0={0,0,0,0}, a1={0,0,0,0}, a2={0,0,0,0}, a3={0,0,0,0},
                a4={0,0,0,0}, a5={0,0,0,0}, a6={0,0,0,0};
        #pragma unroll
        for (int s = 0; s < 3; ++s) {
            a0 = __builtin_amdgcn_mfma_f32_16x16x32_bf16(afr[s], jlo[0][s], a0, 0, 0, 0);
            a1 = __builtin_amdgcn_mfma_f32_16x16x32_bf16(afr[s], jlo[1][s], a1, 0, 0, 0);
            a2 = __builtin_amdgcn_mfma_f32_16x16x32_bf16(afr[s], jlo[2][s], a2, 0, 0, 0);
            a3 = __builtin_amdgcn_mfma_f32_16x16x32_bf16(afr[s], jlo[3][s], a3, 0, 0, 0);
            a4 = __builtin_amdgcn_mfma_f32_16x16x32_bf16(afr[s], jlo[4][s], a4, 0, 0, 0);
            a5 = __builtin_amdgcn_mfma_f32_16x16x32_bf16(afr[s], jlo[5][s], a5, 0, 0, 0);
            a6 = __builtin_amdgcn_mfma_f32_16x16x32_bf16(afr[s], jlo[6][s], a6, 0, 0, 0);
            a0 = __builtin_amdgcn_mfma_f32_16x16x32_bf16(afr[s], jhi[0][s], a0, 0, 0, 0);
            a1 = __builtin_amdgcn_mfma_f32_16x16x32_bf16(afr[s], jhi[1][s], a1, 0, 0, 0);
            a2 = __builtin_amdgcn_mfma_f32_16x16x32_bf16(afr[s], jhi[2][s], a2, 0, 0, 0);
            a3 = __builtin_amdgcn_mfma_f32_16x16x32_bf16(afr[s], jhi[3][s], a3, 0, 0, 0);
            a4 = __builtin_amdgcn_mfma_f32_16x16x32_bf16(afr[s], jhi[4][s], a4, 0, 0, 0);
            a5 = __builtin_amdgcn_mfma_f32_16x16x32_bf16(afr[s], jhi[5][s], a5, 0, 0, 0);
            a6 = __builtin_amdgcn_mfma_f32_16x16x32_bf16(afr[s], jhi[6][s], a6, 0, 0, 0);
        }

        // ---- select this lane's y (compile-time accs, q-cndmask chain) ----
        const float yA0 = (q == 0) ? a0[0] : (q == 1) ? a1[0] : (q == 2) ? a2[0] : a3[0];
        const float yA1 = (q == 0) ? a0[1] : (q == 1) ? a1[1] : (q == 2) ? a2[1] : a3[1];
        const float yB0 = (q == 0) ? a4[0] : (q == 1) ? a5[0] : a6[0];
        const float yB1 = (q == 0) ? a4[1] : (q == 1) ? a5[1] : a6[1];

        // ---- update + r writes (2B each; ~2-way banks) ----
        xA0 = baseA0 + ALPHA * yA0;
        xA1 = baseA1 + ALPHA * yA1;
        __bf16* wb = (__bf16*)rbuf;
        wb[hA]       = (__bf16)fast_tanh(xA0);
        wb[128 + hA] = (__bf16)fast_tanh(xA1);
        if (vB) {
            xB0 = baseB0 + ALPHA * yB0;
            xB1 = baseB1 + ALPHA * yB1;
            wb[hB]       = (__bf16)fast_tanh(xB0);
            wb[128 + hB] = (__bf16)fast_tanh(xB1);
        }
        // refill prefetch slot (vmcnt loads stay in flight; lgkm untouched)
        if (T + 4 < TT) pfetch(T + 4, P);
        // order r-writes before next step's reads (single wave: lgkm only,
        // NO barrier). sched_barrier pins the loop boundary.
        asm volatile("s_waitcnt lgkmcnt(0)" ::: "memory");
        __builtin_amdgcn_sched_barrier(0);
    };

    for (int tb = 0; tb < 748; tb += 4) {
        step(tb + 0, p0);
        step(tb + 1, p1);
        step(tb + 2, p2);
        step(tb + 3, p3);
    }
    step(748, p0);
    step(749, p1);

    // ---- epilogue: out[b] = sum_h tanh(x_final)*Wout[h] + Wout_b ----
    red[0][hA] = fast_tanh(xA0) * wA;
    red[1][hA] = fast_tanh(xA1) * wA;
    if (vB) {
        red[0][hB] = fast_tanh(xB0) * wB;
        red[1][hB] = fast_tanh(xB1) * wB;
    }
    asm volatile("s_waitcnt lgkmcnt(0)" ::: "memory");
    if (lane < 2) {
        float s2 = Wb[0];
        #pragma unroll 4
        for (int i = 0; i < HID; ++i) s2 += red[lane][i];
        out[gb0 + lane] = s2;
    }
}

extern "C" void kernel_launch(void* const* d_in, const int* in_sizes, int n_in,
                              void* d_out, int out_size, void* d_ws, size_t ws_size,
                              hipStream_t stream) {
    rnn_kernel<<<dim3(512), dim3(64), 0, stream>>>(
        (const float*)d_in[0], (const float*)d_in[1], (const float*)d_in[2],
        (const float*)d_in[3], (const float*)d_in[4], (const float*)d_in[5],
        (const float*)d_in[6], (float*)d_out);
}